// Round 4
// baseline (8096.657 us; speedup 1.0000x reference)
//
#include <hip/hip_runtime.h>
#include <stdint.h>
#include <math.h>

#define HH   512
#define BB   64
#define TT   2000
#define NEXC 409          // int(0.8 * 512)
#define SLICE 64          // hidden units owned per block
#define NBAT  4           // batches multiplexed per block (latency hiding)
#define NBLK  128         // 16 quads x 8 slices

// Python-float constants, rounded to f32 exactly as the reference does.
constexpr float ALPHA_F     = 0.1f;
constexpr float IN_SCALE_F  = (float)4.4721359549995794e-03;
constexpr float REC_SCALE_F = (float)4.4721359549995794e-02;
constexpr float SQRT2_F     = 1.41421356237309515f;
constexpr float U_LO        = -0x1.fffffep-1f;

struct U2 { uint32_t a, b; };

__host__ __device__ constexpr uint32_t rotl32(uint32_t x, int d) {
  return (x << d) | (x >> (32 - d));
}

// JAX Threefry-2x32, 20 rounds.
__host__ __device__ constexpr U2 tf2x32(uint32_t k0, uint32_t k1,
                                        uint32_t x0, uint32_t x1) {
  uint32_t ks[3] = {k0, k1, k0 ^ k1 ^ 0x1BD11BDAu};
  const int R[2][4] = {{13, 15, 26, 6}, {17, 29, 16, 24}};
  x0 += ks[0]; x1 += ks[1];
  for (int g = 0; g < 5; ++g) {
    const int* r = R[g & 1];
    for (int i = 0; i < 4; ++i) { x0 += x1; x1 = rotl32(x1, r[i]); x1 ^= x0; }
    x0 += ks[(g + 1) % 3];
    x1 += ks[(g + 2) % 3] + (uint32_t)(g + 1);
  }
  return U2{x0, x1};
}

constexpr U2 KIN_  = tf2x32(0u, 42u, 0u, 0u);
constexpr U2 KREC_ = tf2x32(0u, 42u, 0u, 1u);
constexpr uint32_t KIN0 = KIN_.a,  KIN1 = KIN_.b;
constexpr uint32_t KRC0 = KREC_.a, KRC1 = KREC_.b;

__device__ __forceinline__ float jax_normal(uint32_t k0, uint32_t k1, uint32_t idx) {
  U2 o = tf2x32(k0, k1, 0u, idx);
  uint32_t bits = o.a ^ o.b;
  float f = __uint_as_float((bits >> 9) | 0x3f800000u) - 1.0f;  // [0,1)
  float u = fmaxf(U_LO, f * 2.0f + U_LO);
  float w = -log1pf(-u * u);
  float p;
  if (w < 5.0f) {
    w = w - 2.5f;
    p =             2.81022636e-08f;
    p = fmaf(p, w,  3.43273939e-07f);
    p = fmaf(p, w, -3.5233877e-06f);
    p = fmaf(p, w, -4.39150654e-06f);
    p = fmaf(p, w,  0.00021858087f);
    p = fmaf(p, w, -0.00125372503f);
    p = fmaf(p, w, -0.00417768164f);
    p = fmaf(p, w,  0.246640727f);
    p = fmaf(p, w,  1.50140941f);
  } else {
    w = sqrtf(w) - 3.0f;
    p =            -0.000200214257f;
    p = fmaf(p, w,  0.000100950558f);
    p = fmaf(p, w,  0.00134934322f);
    p = fmaf(p, w, -0.00367342844f);
    p = fmaf(p, w,  0.00573950773f);
    p = fmaf(p, w, -0.0076224613f);
    p = fmaf(p, w,  0.00943887047f);
    p = fmaf(p, w,  1.00167406f);
    p = fmaf(p, w,  2.83297682f);
  }
  return SQRT2_F * (p * u);
}

// Workspace: pub[2][BB][HH] uint64, word = (tag << 32) | f32bits(relu(h)).
// tag t+1 = value after step t. Parity buffer = tag & 1.
#define PUB_WORDS (2 * BB * HH)
#define PUB_BYTES (PUB_WORDS * 8)   // 512 KB

// One phase of one round: batch q of this block's quad.
// RV/HREG/PREQ/PREQM are register NAMES (static indexing; rule: no
// runtime-indexed register arrays). PREQM = pre[(q+3)&3], the batch whose
// new value siblings published one phase ago -> 3 phases in flight.
#define PHASE(Q, RV, HREG, PREQ, PREQM)                                       \
  {                                                                           \
    constexpr int q_  = (Q);                                                  \
    constexpr int qm_ = (q_ + 3) & 3;                                         \
    if (t > 0) {                                                              \
      if (!isOwn) {                                                           \
        uint64_t w_ = PREQ;                                                   \
        if ((uint32_t)(w_ >> 32) != (uint32_t)t) {                            \
          uint64_t* a_ = pub + ((t & 1) ? (size_t)(BB * HH) : 0)              \
                         + (size_t)(b0 + q_) * HH + tid;                      \
          do {                                                                \
            w_ = __hip_atomic_load(a_, __ATOMIC_RELAXED,                      \
                                   __HIP_MEMORY_SCOPE_AGENT);                 \
          } while ((uint32_t)(w_ >> 32) != (uint32_t)t);                      \
        }                                                                     \
        RV = __uint_as_float((uint32_t)w_);                                   \
      }                                                                       \
      if (s == ((t - 1) & 7)) {  /* rotating output duty, off hot path */     \
        float v_ = RV * who_f;                                                \
        for (int o_ = 32; o_ > 0; o_ >>= 1) v_ += __shfl_down(v_, o_);        \
        if (lane == 0) obuf[q_][wv] = v_;                                     \
      }                                                                       \
    }                                                                         \
    float nr_ = 0.f, nA_ = 0.f, nB_ = 0.f, xA_ = 0.f, xB_ = 0.f;              \
    if (isOwn) {                                                              \
      nr_ = nbuf[q_][t & 3][lane];                                            \
      nA_ = nin_s[q_][t & 3][0]; nB_ = nin_s[q_][t & 3][1];                   \
      xA_ = stim_s[q_][t];       xB_ = cc_s[q_][t];                           \
    }                                                                         \
    float acc_ = 0.f;                                                         \
    _Pragma("unroll")                                                         \
    for (int k_ = 0; k_ < 64; ++k_) {                                         \
      float rk_ = __uint_as_float(                                            \
          __builtin_amdgcn_readlane(__float_as_uint(RV), k_));                \
      acc_ = fmaf(rk_, wJ[k_], acc_);                                         \
    }                                                                         \
    red[q_ & 1][wv][lane] = acc_;                                             \
    __syncthreads();                                                          \
    if (isOwn) {                                                              \
      float a2_ = red[q_ & 1][0][lane];                                       \
      _Pragma("unroll")                                                       \
      for (int w2_ = 1; w2_ < 8; ++w2_) a2_ += red[q_ & 1][w2_][lane];        \
      float hh_ = a2_ + bhh + REC_SCALE_F * nr_;                              \
      float c0_ = fmaxf(xA_ + IN_SCALE_F * nA_, 0.f);                         \
      float c1_ = fmaxf(xB_ + IN_SCALE_F * nB_, 0.f);                         \
      float hi_ = c0_ * wih0 + c1_ * wih1;                                    \
      HREG = HREG + (-HREG + hi_ + hh_) * ALPHA_F;                            \
      float r_ = fmaxf(HREG, 0.f);                                            \
      __hip_atomic_store(pub + (((t + 1) & 1) ? (size_t)(BB * HH) : 0)        \
                           + (size_t)(b0 + q_) * HH + tid,                    \
                         ((uint64_t)(uint32_t)(t + 1) << 32) |                \
                             (uint64_t)__float_as_uint(r_),                   \
                         __ATOMIC_RELAXED, __HIP_MEMORY_SCOPE_AGENT);         \
      RV = r_;                                                                \
      __builtin_nontemporal_store(HREG,                                       \
          hids + ((size_t)(b0 + q_) * TT + t) * HH + tid);                    \
    }                                                                         \
    if (!isOwn && !(q_ == 0 && t == 0)) {                                     \
      const uint32_t tau_ = (q_ == 0) ? (uint32_t)t : (uint32_t)(t + 1);      \
      PREQM = __hip_atomic_load(                                              \
          pub + ((tau_ & 1) ? (size_t)(BB * HH) : 0)                          \
            + (size_t)(b0 + qm_) * HH + tid,                                  \
          __ATOMIC_RELAXED, __HIP_MEMORY_SCOPE_AGENT);                        \
    }                                                                         \
    if (t > 0 && s == ((t - 1) & 7) && tid == 0) {                            \
      float p_ = ((obuf[q_][0] + obuf[q_][1]) + (obuf[q_][2] + obuf[q_][3]))  \
               + ((obuf[q_][4] + obuf[q_][5]) + (obuf[q_][6] + obuf[q_][7])); \
      outs[(b0 + q_) * TT + (t - 1)] = p_ + bho;                              \
    }                                                                         \
  }

// Tail consume for the final output (tag TT), with fresh-poll fallback.
#define TAILQ(Q, RV, PREQ)                                                    \
  {                                                                           \
    constexpr int q_ = (Q);                                                   \
    if (!isOwn) {                                                             \
      uint64_t w_ = PREQ;                                                     \
      if ((uint32_t)(w_ >> 32) != (uint32_t)TT) {                             \
        uint64_t* a_ = pub + ((TT & 1) ? (size_t)(BB * HH) : 0)               \
                       + (size_t)(b0 + q_) * HH + tid;                        \
        do {                                                                  \
          w_ = __hip_atomic_load(a_, __ATOMIC_RELAXED,                        \
                                 __HIP_MEMORY_SCOPE_AGENT);                   \
        } while ((uint32_t)(w_ >> 32) != (uint32_t)TT);                       \
      }                                                                       \
      RV = __uint_as_float((uint32_t)w_);                                     \
    }                                                                         \
    float v_ = RV * who_f;                                                    \
    for (int o_ = 32; o_ > 0; o_ >>= 1) v_ += __shfl_down(v_, o_);            \
    if (lane == 0) obuf[q_][wv] = v_;                                         \
  }

__global__ __launch_bounds__(512, 1)
void zrnn_main(const float* __restrict__ i_stim, const float* __restrict__ i_cc,
               const float* __restrict__ hidden0,
               const float* __restrict__ w_ih, const float* __restrict__ w_hh,
               const float* __restrict__ b_hh,
               const float* __restrict__ w_ho, const float* __restrict__ b_ho,
               float* __restrict__ outs, float* __restrict__ hids,
               uint64_t* __restrict__ pub) {
  // bid = s*16 + g: quad g (batches 4g..4g+3), slice s (units [64s,64s+64)).
  // bid%8 == g%8 -> all 8 slice-siblings of a quad share an XCD under
  // round-robin dispatch (perf-only assumption).
  const int bid  = blockIdx.x;
  const int g    = bid & 15;
  const int s    = bid >> 4;
  const int b0   = g * 4;
  const int tid  = threadIdx.x;
  const int lane = tid & 63;
  const int wv   = tid >> 6;

  const int  ownLo = s * SLICE;
  const bool isOwn = (wv == s);   // owner wave: thread tid owns unit j == tid

  __shared__ float stim_s[NBAT][TT];     // 32 KB
  __shared__ float cc_s[NBAT][TT];       // 32 KB
  __shared__ float red[2][8][SLICE];     // 4 KB, phase-parity reuse
  __shared__ float nbuf[NBAT][4][SLICE]; // 4 KB, n_rec 4 steps ahead
  __shared__ float nin_s[NBAT][4][2];
  __shared__ float obuf[NBAT][8];

  // Preload the quad's input streams, coalesced.
  #pragma unroll
  for (int q = 0; q < NBAT; ++q)
    for (int idx = tid; idx < TT; idx += 512) {
      stim_s[q][idx] = i_stim[(b0 + q) * TT + idx];
      cc_s[q][idx]   = i_cc[(b0 + q) * TT + idx];
    }

  // Weight slice in REGISTERS (batch-invariant): thread (wv,lane) holds
  // wt[i][jA] for i in [64wv, 64wv+64), jA = ownLo+lane.
  // wt[i][j] = |w_hh[j][i]| * (i!=j) * ei[i].
  const int jA = ownLo + lane;
  const int i0 = wv * 64;
  float wJ[64];
  #pragma unroll
  for (int k4 = 0; k4 < 16; ++k4) {
    float4 a4 = *reinterpret_cast<const float4*>(&w_hh[jA * HH + i0 + k4 * 4]);
    const float av[4] = {a4.x, a4.y, a4.z, a4.w};
    #pragma unroll
    for (int c = 0; c < 4; ++c) {
      const int i = i0 + k4 * 4 + c;
      float va = (i == jA) ? 0.0f : fabsf(av[c]);
      wJ[k4 * 4 + c] = (i < NEXC) ? va : -va;
    }
  }

  // Owner state (unit j == tid), shared weights across the 4 batches.
  float h0 = 0.f, h1 = 0.f, h2 = 0.f, h3 = 0.f;
  float wih0 = 0.f, wih1 = 0.f, bhh = 0.f;
  if (isOwn) {
    h0 = hidden0[(b0 + 0) * HH + tid];
    h1 = hidden0[(b0 + 1) * HH + tid];
    h2 = hidden0[(b0 + 2) * HH + tid];
    h3 = hidden0[(b0 + 3) * HH + tid];
    wih0 = w_ih[tid * 2 + 0];
    wih1 = w_ih[tid * 2 + 1];
    bhh  = b_hh[tid];
  }
  const float who_f = w_ho[tid];
  const float bho   = b_ho[0];

  // rv_q: lane-mapped relu(h) vectors (i = tid), primed from hidden0.
  float rv0 = fmaxf(hidden0[(b0 + 0) * HH + tid], 0.f);
  float rv1 = fmaxf(hidden0[(b0 + 1) * HH + tid], 0.f);
  float rv2 = fmaxf(hidden0[(b0 + 2) * HH + tid], 0.f);
  float rv3 = fmaxf(hidden0[(b0 + 3) * HH + tid], 0.f);

  // Noise prefill for steps 0..3: 4 batches x 4 steps x 64 units = 1024
  // normals over 512 threads (2 each).
  for (int e = tid; e < NBAT * 4 * SLICE; e += 512) {
    const int q  = e >> 8;
    const int tp = (e >> 6) & 3;
    const int jn = e & 63;
    nbuf[q][tp][jn] = jax_normal(KRC0, KRC1,
        (uint32_t)tp * (uint32_t)(BB * HH) +
        (uint32_t)((b0 + q) * HH + ownLo + jn));
  }
  if (tid < NBAT * 4 * 2) {
    const int q  = tid >> 3;
    const int tp = (tid >> 1) & 3;
    const int sl = tid & 1;
    nin_s[q][tp][sl] = jax_normal(KIN0, KIN1,
        (uint32_t)(tp * (BB * 2) + (b0 + q) * 2 + sl));
  }

  uint64_t pre0 = 0, pre1 = 0, pre2 = 0, pre3 = 0;

  __syncthreads();

  for (int t = 0; t < TT; ++t) {
    PHASE(0, rv0, h0, pre0, pre3)
    PHASE(1, rv1, h1, pre1, pre0)
    PHASE(2, rv2, h2, pre2, pre1)
    PHASE(3, rv3, h3, pre3, pre2)

    // Noise for step t+4, on non-owner waves only (owner wave stays on the
    // publish path). Slot (t+4)&3 == t&3; all round-t reads are pre-barrier-3,
    // these writes are post-barrier-3; reads at t+4 are >=4 barriers later.
    if (t + 4 < TT) {
      const int d = (wv - s - 1) & 7;   // d<4: n_rec batch d; d==4: n_in
      if (d < 4) {
        nbuf[d][t & 3][lane] = jax_normal(KRC0, KRC1,
            (uint32_t)(t + 4) * (uint32_t)(BB * HH) +
            (uint32_t)((b0 + d) * HH + ownLo + lane));
      } else if (d == 4 && lane < 8) {
        const int q2 = lane >> 1, sl = lane & 1;
        nin_s[q2][t & 3][sl] = jax_normal(KIN0, KIN1,
            (uint32_t)((t + 4) * (BB * 2) + (b0 + q2) * 2 + sl));
      }
    }
  }

  // Final outputs outs[.][TT-1] need tag TT; duty slice only.
  if (s == ((TT - 1) & 7)) {
    TAILQ(0, rv0, pre0)
    TAILQ(1, rv1, pre1)
    TAILQ(2, rv2, pre2)
    TAILQ(3, rv3, pre3)
    __syncthreads();
    if (tid < NBAT) {
      float p_ = ((obuf[tid][0] + obuf[tid][1]) + (obuf[tid][2] + obuf[tid][3])) +
                 ((obuf[tid][4] + obuf[tid][5]) + (obuf[tid][6] + obuf[tid][7]));
      outs[(b0 + tid) * TT + (TT - 1)] = p_ + bho;
    }
  }
}

extern "C" void kernel_launch(void* const* d_in, const int* in_sizes, int n_in,
                              void* d_out, int out_size, void* d_ws, size_t ws_size,
                              hipStream_t stream) {
  const float* i_stim = (const float*)d_in[0];
  const float* i_cc   = (const float*)d_in[1];
  const float* hidden = (const float*)d_in[2];
  const float* w_ih   = (const float*)d_in[3];
  // d_in[4] = b_ih — never used by the reference
  const float* w_hh   = (const float*)d_in[5];
  const float* b_hh   = (const float*)d_in[6];
  const float* w_ho   = (const float*)d_in[7];
  const float* b_ho   = (const float*)d_in[8];

  float* outs   = (float*)d_out;                     // [B,T,O]
  float* hids   = (float*)d_out + (size_t)BB * TT;   // [B,T,H]
  uint64_t* pub = (uint64_t*)d_ws;

  // Kill stale tags from previous graph replays (tags strictly increase
  // within a run, so zeroed words can never falsely match).
  hipMemsetAsync(pub, 0, PUB_BYTES, stream);

  void* args[] = {(void*)&i_stim, (void*)&i_cc, (void*)&hidden, (void*)&w_ih,
                  (void*)&w_hh, (void*)&b_hh, (void*)&w_ho, (void*)&b_ho,
                  (void*)&outs, (void*)&hids, (void*)&pub};
  hipLaunchCooperativeKernel((const void*)zrnn_main, dim3(NBLK), dim3(512),
                             args, 0, stream);
}

// Round 5
// 4298.082 us; speedup vs baseline: 1.8838x; 1.8838x over previous
//
#include <hip/hip_runtime.h>
#include <stdint.h>
#include <math.h>

#define HH   512
#define BB   64
#define TT   2000
#define NEXC 409          // int(0.8 * 512)
#define SLICE 64          // hidden units owned per block
#define NBLK  256         // 32 pairs x 8 slices = full machine
#define PUBH  ((size_t)(BB * HH))

// Python-float constants, rounded to f32 exactly as the reference does.
constexpr float ALPHA_F     = 0.1f;
constexpr float IN_SCALE_F  = (float)4.4721359549995794e-03;
constexpr float REC_SCALE_F = (float)4.4721359549995794e-02;
constexpr float SQRT2_F     = 1.41421356237309515f;
constexpr float U_LO        = -0x1.fffffep-1f;

struct U2 { uint32_t a, b; };

__host__ __device__ constexpr uint32_t rotl32(uint32_t x, int d) {
  return (x << d) | (x >> (32 - d));
}

// JAX Threefry-2x32, 20 rounds.
__host__ __device__ constexpr U2 tf2x32(uint32_t k0, uint32_t k1,
                                        uint32_t x0, uint32_t x1) {
  uint32_t ks[3] = {k0, k1, k0 ^ k1 ^ 0x1BD11BDAu};
  const int R[2][4] = {{13, 15, 26, 6}, {17, 29, 16, 24}};
  x0 += ks[0]; x1 += ks[1];
  for (int g = 0; g < 5; ++g) {
    const int* r = R[g & 1];
    for (int i = 0; i < 4; ++i) { x0 += x1; x1 = rotl32(x1, r[i]); x1 ^= x0; }
    x0 += ks[(g + 1) % 3];
    x1 += ks[(g + 2) % 3] + (uint32_t)(g + 1);
  }
  return U2{x0, x1};
}

constexpr U2 KIN_  = tf2x32(0u, 42u, 0u, 0u);
constexpr U2 KREC_ = tf2x32(0u, 42u, 0u, 1u);
constexpr uint32_t KIN0 = KIN_.a,  KIN1 = KIN_.b;
constexpr uint32_t KRC0 = KREC_.a, KRC1 = KREC_.b;

__device__ __forceinline__ float jax_normal(uint32_t k0, uint32_t k1, uint32_t idx) {
  U2 o = tf2x32(k0, k1, 0u, idx);
  uint32_t bits = o.a ^ o.b;
  float f = __uint_as_float((bits >> 9) | 0x3f800000u) - 1.0f;  // [0,1)
  float u = fmaxf(U_LO, f * 2.0f + U_LO);
  float w = -log1pf(-u * u);
  float p;
  if (w < 5.0f) {
    w = w - 2.5f;
    p =             2.81022636e-08f;
    p = fmaf(p, w,  3.43273939e-07f);
    p = fmaf(p, w, -3.5233877e-06f);
    p = fmaf(p, w, -4.39150654e-06f);
    p = fmaf(p, w,  0.00021858087f);
    p = fmaf(p, w, -0.00125372503f);
    p = fmaf(p, w, -0.00417768164f);
    p = fmaf(p, w,  0.246640727f);
    p = fmaf(p, w,  1.50140941f);
  } else {
    w = sqrtf(w) - 3.0f;
    p =            -0.000200214257f;
    p = fmaf(p, w,  0.000100950558f);
    p = fmaf(p, w,  0.00134934322f);
    p = fmaf(p, w, -0.00367342844f);
    p = fmaf(p, w,  0.00573950773f);
    p = fmaf(p, w, -0.0076224613f);
    p = fmaf(p, w,  0.00943887047f);
    p = fmaf(p, w,  1.00167406f);
    p = fmaf(p, w,  2.83297682f);
  }
  return SQRT2_F * (p * u);
}

// Workspace: pub[2][BB][HH] uint64, word = (tag << 32) | f32bits(relu(h)).
// tag t+1 = value after step t; slot parity = tag & 1.
#define PUB_BYTES (2 * BB * HH * 8)   // 512 KB

// One phase = one step of one batch. Q is constexpr; RV/HREG/PREQ/PREOTH are
// register NAMES (static indexing only). PREOTH prefetches the OTHER batch's
// next consume-tag, issued mid-phase (>= ~600 cyc after its publish) so it
// samples past the store->visible window and its latency rides the barrier.
#define PHASE(Q, RV, HREG, PREQ, PREOTH, BQ, BOTH)                            \
  {                                                                           \
    if (t > 0) {                                                              \
      if (!isOwn) {                                                           \
        uint64_t w_ = PREQ;                                                   \
        if ((uint32_t)(w_ >> 32) != (uint32_t)t) {                            \
          uint64_t* a_ = pub + ((t & 1) ? PUBH : 0) + (size_t)(BQ) * HH + tid;\
          do {                                                                \
            w_ = __hip_atomic_load(a_, __ATOMIC_RELAXED,                      \
                                   __HIP_MEMORY_SCOPE_AGENT);                 \
          } while ((uint32_t)(w_ >> 32) != (uint32_t)t);                      \
        }                                                                     \
        RV = __uint_as_float((uint32_t)w_);                                   \
      }                                                                       \
      if (s == ((t - 1) & 7)) {  /* rotating output duty, off hot path */     \
        float v_ = RV * who_f;                                                \
        for (int o_ = 32; o_ > 0; o_ >>= 1) v_ += __shfl_down(v_, o_);        \
        if (lane == 0) obuf[Q][wv] = v_;                                      \
      }                                                                       \
    }                                                                         \
    float nr_ = 0.f, nA_ = 0.f, nB_ = 0.f, xA_ = 0.f, xB_ = 0.f;              \
    if (isOwn) {                                                              \
      nr_ = nbuf[Q][t & 3][lane];                                             \
      nA_ = nin_s[Q][t & 3][0]; nB_ = nin_s[Q][t & 3][1];                     \
      xA_ = stim_s[Q][t];       xB_ = cc_s[Q][t];                             \
    }                                                                         \
    float acc_ = 0.f;                                                         \
    _Pragma("unroll")                                                         \
    for (int k_ = 0; k_ < 64; ++k_) {                                         \
      float rk_ = __uint_as_float(                                            \
          __builtin_amdgcn_readlane(__float_as_uint(RV), k_));                \
      acc_ = fmaf(rk_, wJ[k_], acc_);                                         \
    }                                                                         \
    red[Q][wv][lane] = acc_;                                                  \
    if (!isOwn) {                                                             \
      const uint32_t tg_ = (Q == 0) ? (uint32_t)t : (uint32_t)(t + 1);        \
      PREOTH = __hip_atomic_load(                                             \
          pub + ((tg_ & 1) ? PUBH : 0) + (size_t)(BOTH) * HH + tid,           \
          __ATOMIC_RELAXED, __HIP_MEMORY_SCOPE_AGENT);                        \
    }                                                                         \
    __syncthreads();                                                          \
    if (isOwn) {                                                              \
      float a2_ = red[Q][0][lane];                                            \
      _Pragma("unroll")                                                       \
      for (int w2_ = 1; w2_ < 8; ++w2_) a2_ += red[Q][w2_][lane];             \
      float hh_ = a2_ + bhh + REC_SCALE_F * nr_;                              \
      float c0_ = fmaxf(xA_ + IN_SCALE_F * nA_, 0.f);                         \
      float c1_ = fmaxf(xB_ + IN_SCALE_F * nB_, 0.f);                         \
      float hi_ = c0_ * wih0 + c1_ * wih1;                                    \
      HREG = HREG + (-HREG + hi_ + hh_) * ALPHA_F;                            \
      float r_ = fmaxf(HREG, 0.f);                                            \
      __hip_atomic_store(pub + (((t + 1) & 1) ? PUBH : 0) +                   \
                             (size_t)(BQ) * HH + tid,                         \
                         ((uint64_t)(uint32_t)(t + 1) << 32) |                \
                             (uint64_t)__float_as_uint(r_),                   \
                         __ATOMIC_RELAXED, __HIP_MEMORY_SCOPE_AGENT);         \
      RV = r_;                                                                \
      __builtin_nontemporal_store(HREG,                                       \
          hids + ((size_t)(BQ) * TT + t) * HH + tid);                         \
    }                                                                         \
    if (t > 0 && s == ((t - 1) & 7) && tid == finTid) {                       \
      float p_ = ((obuf[Q][0] + obuf[Q][1]) + (obuf[Q][2] + obuf[Q][3])) +    \
                 ((obuf[Q][4] + obuf[Q][5]) + (obuf[Q][6] + obuf[Q][7]));     \
      outs[(BQ) * TT + (t - 1)] = p_ + bho;                                   \
    }                                                                         \
  }

__global__ __launch_bounds__(512, 1)
void zrnn_main(const float* __restrict__ i_stim, const float* __restrict__ i_cc,
               const float* __restrict__ hidden0,
               const float* __restrict__ w_ih, const float* __restrict__ w_hh,
               const float* __restrict__ b_hh,
               const float* __restrict__ w_ho, const float* __restrict__ b_ho,
               float* __restrict__ outs, float* __restrict__ hids,
               uint64_t* __restrict__ pub) {
  // bid = s*32 + g: pair g (batches 2g,2g+1), slice s (units [64s,64s+64)).
  // bid&7 == g&7 -> all 8 slice-siblings of a pair share an XCD under
  // round-robin dispatch (perf-only assumption).
  const int bid  = blockIdx.x;
  const int g    = bid & 31;
  const int s    = bid >> 5;
  const int bA   = 2 * g;
  const int bB   = 2 * g + 1;
  const int tid  = threadIdx.x;
  const int lane = tid & 63;
  const int wv   = tid >> 6;

  const int  ownLo  = s * SLICE;
  const bool isOwn  = (wv == s);           // owner wave: unit j == tid
  const int  finTid = ((s + 4) & 7) << 6;  // duty finalizer (non-owner wave)

  __shared__ float stim_s[2][TT];     // 16 KB
  __shared__ float cc_s[2][TT];       // 16 KB
  __shared__ float red[2][8][SLICE];  // 4 KB, per-phase partials
  __shared__ float nbuf[2][4][SLICE]; // n_rec, 4 steps ahead
  __shared__ float nin_s[2][4][2];    // n_in
  __shared__ float obuf[2][8];        // output-duty partials

  // Preload the pair's input streams, coalesced.
  for (int idx = tid; idx < TT; idx += 512) {
    stim_s[0][idx] = i_stim[bA * TT + idx];
    stim_s[1][idx] = i_stim[bB * TT + idx];
    cc_s[0][idx]   = i_cc[bA * TT + idx];
    cc_s[1][idx]   = i_cc[bB * TT + idx];
  }

  // Weight slice in REGISTERS (shared by both batches): thread (wv,lane)
  // holds wt[i][jA] for i in [64wv, 64wv+64), jA = ownLo+lane.
  // wt[i][j] = |w_hh[j][i]| * (i!=j) * ei[i].
  const int jA = ownLo + lane;
  const int i0 = wv * 64;
  float wJ[64];
  #pragma unroll
  for (int k4 = 0; k4 < 16; ++k4) {
    float4 a4 = *reinterpret_cast<const float4*>(&w_hh[jA * HH + i0 + k4 * 4]);
    const float av[4] = {a4.x, a4.y, a4.z, a4.w};
    #pragma unroll
    for (int c = 0; c < 4; ++c) {
      const int i = i0 + k4 * 4 + c;
      float va = (i == jA) ? 0.0f : fabsf(av[c]);
      wJ[k4 * 4 + c] = (i < NEXC) ? va : -va;
    }
  }

  // Owner state (unit j == tid), weights shared across the 2 batches.
  float h0 = 0.f, h1 = 0.f, wih0 = 0.f, wih1 = 0.f, bhh = 0.f;
  if (isOwn) {
    h0   = hidden0[bA * HH + tid];
    h1   = hidden0[bB * HH + tid];
    wih0 = w_ih[tid * 2 + 0];
    wih1 = w_ih[tid * 2 + 1];
    bhh  = b_hh[tid];
  }
  const float who_f = w_ho[tid];
  const float bho   = b_ho[0];

  // rv: thread tid holds relu(h[i = tid]) per batch, primed from hidden0.
  float rv0 = fmaxf(hidden0[bA * HH + tid], 0.f);
  float rv1 = fmaxf(hidden0[bB * HH + tid], 0.f);

  // Noise prefill for steps 0..3: 2 batches x 4 steps x 64 units = 512.
  {
    const int q  = tid >> 8;
    const int tp = (tid >> 6) & 3;
    const int jn = tid & 63;
    nbuf[q][tp][jn] = jax_normal(KRC0, KRC1,
        (uint32_t)tp * (uint32_t)(BB * HH) +
        (uint32_t)((bA + q) * HH + ownLo + jn));
    if (tid < 16) {
      const int q2  = tid >> 3;
      const int tp2 = (tid >> 1) & 3;
      const int sl  = tid & 1;
      nin_s[q2][tp2][sl] = jax_normal(KIN0, KIN1,
          (uint32_t)(tp2 * (BB * 2) + (bA + q2) * 2 + sl));
    }
  }

  uint64_t pre0 = 0, pre1 = 0;

  __syncthreads();

  for (int t = 0; t < TT; ++t) {
    PHASE(0, rv0, h0, pre0, pre1, bA, bB)   // phase A: batch bA
    PHASE(1, rv1, h1, pre1, pre0, bB, bA)   // phase B: batch bB

    // Noise for step t+4 on designated non-owner waves (post-barrier-B;
    // reads of slot t&3 for step t+4 are >= 2 barriers away).
    if (t + 4 < TT) {
      const int dw = (wv - s) & 7;
      if (dw == 1) {
        nbuf[0][t & 3][lane] = jax_normal(KRC0, KRC1,
            (uint32_t)(t + 4) * (uint32_t)(BB * HH) +
            (uint32_t)(bA * HH + ownLo + lane));
      } else if (dw == 2) {
        nbuf[1][t & 3][lane] = jax_normal(KRC0, KRC1,
            (uint32_t)(t + 4) * (uint32_t)(BB * HH) +
            (uint32_t)(bB * HH + ownLo + lane));
      } else if (dw == 3 && lane < 4) {
        nin_s[lane >> 1][t & 3][lane & 1] = jax_normal(KIN0, KIN1,
            (uint32_t)((t + 4) * (BB * 2) + (bA + (lane >> 1)) * 2 + (lane & 1)));
      }
    }
  }

  // Tail: outs[.][TT-1] needs tag TT; duty slice only.
  if (s == ((TT - 1) & 7)) {
    if (!isOwn) {
      uint64_t w_ = pre0;
      if ((uint32_t)(w_ >> 32) != (uint32_t)TT) {
        uint64_t* a_ = pub + ((TT & 1) ? PUBH : 0) + (size_t)bA * HH + tid;
        do {
          w_ = __hip_atomic_load(a_, __ATOMIC_RELAXED, __HIP_MEMORY_SCOPE_AGENT);
        } while ((uint32_t)(w_ >> 32) != (uint32_t)TT);
      }
      rv0 = __uint_as_float((uint32_t)w_);
      w_ = pre1;
      if ((uint32_t)(w_ >> 32) != (uint32_t)TT) {
        uint64_t* a_ = pub + ((TT & 1) ? PUBH : 0) + (size_t)bB * HH + tid;
        do {
          w_ = __hip_atomic_load(a_, __ATOMIC_RELAXED, __HIP_MEMORY_SCOPE_AGENT);
        } while ((uint32_t)(w_ >> 32) != (uint32_t)TT);
      }
      rv1 = __uint_as_float((uint32_t)w_);
    }
    float v0 = rv0 * who_f;
    float v1 = rv1 * who_f;
    for (int o_ = 32; o_ > 0; o_ >>= 1) {
      v0 += __shfl_down(v0, o_);
      v1 += __shfl_down(v1, o_);
    }
    if (lane == 0) { obuf[0][wv] = v0; obuf[1][wv] = v1; }
    __syncthreads();
    if (tid < 2) {
      float p_ = ((obuf[tid][0] + obuf[tid][1]) + (obuf[tid][2] + obuf[tid][3])) +
                 ((obuf[tid][4] + obuf[tid][5]) + (obuf[tid][6] + obuf[tid][7]));
      outs[(bA + tid) * TT + (TT - 1)] = p_ + bho;
    }
  }
}

extern "C" void kernel_launch(void* const* d_in, const int* in_sizes, int n_in,
                              void* d_out, int out_size, void* d_ws, size_t ws_size,
                              hipStream_t stream) {
  const float* i_stim = (const float*)d_in[0];
  const float* i_cc   = (const float*)d_in[1];
  const float* hidden = (const float*)d_in[2];
  const float* w_ih   = (const float*)d_in[3];
  // d_in[4] = b_ih — never used by the reference
  const float* w_hh   = (const float*)d_in[5];
  const float* b_hh   = (const float*)d_in[6];
  const float* w_ho   = (const float*)d_in[7];
  const float* b_ho   = (const float*)d_in[8];

  float* outs   = (float*)d_out;                     // [B,T,O]
  float* hids   = (float*)d_out + (size_t)BB * TT;   // [B,T,H]
  uint64_t* pub = (uint64_t*)d_ws;

  // Kill stale tags from previous graph replays (tags strictly increase
  // within a run, so zeroed words can never falsely match).
  hipMemsetAsync(pub, 0, PUB_BYTES, stream);

  void* args[] = {(void*)&i_stim, (void*)&i_cc, (void*)&hidden, (void*)&w_ih,
                  (void*)&w_hh, (void*)&b_hh, (void*)&w_ho, (void*)&b_ho,
                  (void*)&outs, (void*)&hids, (void*)&pub};
  hipLaunchCooperativeKernel((const void*)zrnn_main, dim3(NBLK), dim3(512),
                             args, 0, stream);
}